// Round 4
// baseline (82.914 us; speedup 1.0000x reference)
//
#include <hip/hip_runtime.h>

#define NATOMS 13
#define NP (NATOMS * NATOMS)   // 169

constexpr int N_ = 1024;   // rows
constexpr int H_ = 512;    // inner dim
constexpr int O_ = 512;    // output dim
constexpr int RB = 8;      // rows per W stream (oct)
constexpr int HSPLIT = 4;
constexpr int HH = H_ / HSPLIT;                    // 128
constexpr int MAXOCT = (N_ + (RB - 1) * NP) / RB + 1;  // 276 upper bound
constexpr int NB = MAXOCT * HSPLIT;                // 1104 blocks
constexpr int RECS = 12;   // ints per oct record: rows[8], id, pad

// ws ints: [0] nocts; [16 + oct*RECS + {0..7}] rows (-1 pad), [+8] group id
// ------------------------------------------------------------------ build octs
__global__ void build_octs(const int* __restrict__ x,
                           const int* __restrict__ fact,
                           int* __restrict__ ws, int N) {
    __shared__ int s_id[N_];
    __shared__ int s_cnt[NP];
    __shared__ int s_start[NP];
    __shared__ int s_ostart[NP];
    __shared__ int s_pos[NP];
    __shared__ int s_sorted[N_];
    const int tid = threadIdx.x, bd = blockDim.x;

    for (int i = tid; i < NP; i += bd) { s_cnt[i] = 0; s_pos[i] = 0; }
    __syncthreads();
    for (int n = tid; n < N; n += bd) {
        const int f0 = fact[2 * n];
        const int id = x[f0 * 3 + 1] * NATOMS + x[f0 * 3 + 2];
        s_id[n] = id;
        atomicAdd(&s_cnt[id], 1);
    }
    __syncthreads();
    if (tid == 0) {
        int run = 0, orun = 0;
        for (int g = 0; g < NP; ++g) {
            s_start[g] = run;   run  += s_cnt[g];
            s_ostart[g] = orun; orun += (s_cnt[g] + RB - 1) / RB;
        }
        ws[0] = orun;  // nocts
    }
    __syncthreads();
    for (int n = tid; n < N; n += bd) {
        const int id = s_id[n];
        const int p = atomicAdd(&s_pos[id], 1);
        s_sorted[s_start[id] + p] = n;
    }
    __syncthreads();
    for (int g = tid; g < NP; g += bd) {
        const int c = s_cnt[g], st = s_start[g], os = s_ostart[g];
        const int no = (c + RB - 1) / RB;
        for (int k = 0; k < no; ++k) {
            int* rec = ws + 16 + (size_t)(os + k) * RECS;
            for (int r = 0; r < RB; ++r) {
                const int idx = k * RB + r;
                rec[r] = (idx < c) ? s_sorted[st + idx] : -1;
            }
            rec[RB] = g;
        }
    }
}

// ------------------------------------------------------------------- oct GEMV
// One block per (oct, h-slab). Streams W[id][h0:h0+128, :] once with float4
// loads and applies it to all 8 rows of the oct (32 FMA / 16B load).
__global__ __launch_bounds__(128)
void oct_gemv(const int* __restrict__ ws,
              const float* __restrict__ inp,
              const float* __restrict__ params,
              const float* __restrict__ bias,
              const int* __restrict__ msg_to_p,
              const int* __restrict__ order_p,
              float* __restrict__ out, int N) {
    // bijective XCD-chunked swizzle (NB % 8 == 0): consecutive logical blocks
    // (h-slabs of one oct, neighboring octs of one group) share an XCD.
    constexpr int q = NB / 8;
    const int b = blockIdx.x;
    const int Lg = (b & 7) * q + (b >> 3);
    const int oct = Lg >> 2;        // / HSPLIT
    const int ht  = Lg & 3;

    if (oct >= ws[0]) return;
    const int* rec = ws + 16 + (size_t)oct * RECS;
    const int id = rec[RB];

    const int msg_to = *msg_to_p;
    const int order  = *order_p;
    const int tid = threadIdx.x;
    const int h0 = ht * HH;

    __shared__ float fp_s[HH][RB];   // [h][r] — 16B-aligned row groups
    // stage: HH == blockDim → one h per thread per row
#pragma unroll
    for (int r = 0; r < RB; ++r) {
        const int row = rec[r];
        float p = 0.0f;
        if (row >= 0) {
            p = 1.0f;
            for (int i = 0; i < order; ++i)
                if (i != msg_to)
                    p *= inp[((size_t)i * N + row) * H_ + h0 + tid];
        }
        fp_s[tid][r] = p;
    }
    __syncthreads();

    const float* wp = params + (size_t)id * H_ * O_ + (size_t)h0 * O_ + 4 * tid;

    float4 a0 = make_float4(0,0,0,0), a1 = a0, a2 = a0, a3 = a0;
    float4 a4 = a0, a5 = a0, a6 = a0, a7 = a0;

#define FMA1(acc, s) acc.x += (s) * w.x; acc.y += (s) * w.y; \
                     acc.z += (s) * w.z; acc.w += (s) * w.w;
#pragma unroll 4
    for (int h = 0; h < HH; ++h) {
        const float4 w  = *(const float4*)wp;  wp += O_;
        const float4 fA = *(const float4*)&fp_s[h][0];
        const float4 fB = *(const float4*)&fp_s[h][4];
        FMA1(a0, fA.x) FMA1(a1, fA.y) FMA1(a2, fA.z) FMA1(a3, fA.w)
        FMA1(a4, fB.x) FMA1(a5, fB.y) FMA1(a6, fB.z) FMA1(a7, fB.w)
    }
#undef FMA1

    float4 bv = make_float4(0,0,0,0);
    if (ht == 0) bv = *(const float4*)(bias + (size_t)id * O_ + 4 * tid);

#define EMIT(r, acc)                                                   \
    { const int row = rec[r];                                          \
      if (row >= 0) {                                                  \
          float* op = out + (size_t)row * O_ + 4 * tid;                \
          atomicAdd(op + 0, acc.x + bv.x);                             \
          atomicAdd(op + 1, acc.y + bv.y);                             \
          atomicAdd(op + 2, acc.z + bv.z);                             \
          atomicAdd(op + 3, acc.w + bv.w);                             \
      } }
    EMIT(0, a0) EMIT(1, a1) EMIT(2, a2) EMIT(3, a3)
    EMIT(4, a4) EMIT(5, a5) EMIT(6, a6) EMIT(7, a7)
#undef EMIT
}

// ---------------------------------------------------------------------- launch
extern "C" void kernel_launch(void* const* d_in, const int* in_sizes, int n_in,
                              void* d_out, int out_size, void* d_ws, size_t ws_size,
                              hipStream_t stream) {
    const int*   x      = (const int*)d_in[0];
    const int*   fact   = (const int*)d_in[1];
    const float* inp    = (const float*)d_in[2];
    const float* params = (const float*)d_in[3];
    const float* bias   = (const float*)d_in[4];
    const int*   msg_to = (const int*)d_in[5];
    const int*   order  = (const int*)d_in[6];
    float*       out    = (float*)d_out;

    const int N = in_sizes[1] / 2;   // 1024
    int* ws = (int*)d_ws;

    hipMemsetAsync(d_out, 0, (size_t)N * O_ * sizeof(float), stream);

    hipLaunchKernelGGL(build_octs, dim3(1), dim3(256), 0, stream,
                       x, fact, ws, N);

    hipLaunchKernelGGL(oct_gemv, dim3(NB), dim3(128), 0, stream,
                       ws, inp, params, bias, msg_to, order, out, N);
}

// Round 5
// 75.820 us; speedup vs baseline: 1.0936x; 1.0936x over previous
//
#include <hip/hip_runtime.h>

#define NATOMS 13
#define NP (NATOMS * NATOMS)   // 169

constexpr int N_ = 1024;   // rows
constexpr int H_ = 512;    // inner dim
constexpr int O_ = 512;    // output dim
constexpr int RB = 4;      // rows per W stream (quad)
constexpr int HSPLIT = 4;
constexpr int HH = H_ / HSPLIT;   // 128
constexpr int MAXQUAD = 384;      // >= sum ceil(c_g/4) worst case (256+127)
constexpr int NB = MAXQUAD * HSPLIT;  // 1536 blocks (div by 8)
constexpr int RECS = 8;    // ints per quad record: rows[4], id, pad

// ws ints: [0] nquads; records at ws+16: [quad*RECS + {0..3}] rows, [+4] id
// ----------------------------------------------------------------- build quads
__global__ void build_quads(const int* __restrict__ x,
                            const int* __restrict__ fact,
                            int* __restrict__ ws, int N) {
    __shared__ int s_id[N_];
    __shared__ int s_cnt[NP];
    __shared__ int s_start[NP];
    __shared__ int s_qstart[NP];
    __shared__ int s_pos[NP];
    __shared__ int s_sorted[N_];
    const int tid = threadIdx.x, bd = blockDim.x;

    for (int i = tid; i < NP; i += bd) { s_cnt[i] = 0; s_pos[i] = 0; }
    __syncthreads();
    for (int n = tid; n < N; n += bd) {
        const int f0 = fact[2 * n];
        const int id = x[f0 * 3 + 1] * NATOMS + x[f0 * 3 + 2];
        s_id[n] = id;
        atomicAdd(&s_cnt[id], 1);
    }
    __syncthreads();
    if (tid == 0) {
        int run = 0, qrun = 0;
        for (int g = 0; g < NP; ++g) {
            s_start[g] = run;   run  += s_cnt[g];
            s_qstart[g] = qrun; qrun += (s_cnt[g] + RB - 1) / RB;
        }
        ws[0] = qrun;  // nquads
    }
    __syncthreads();
    for (int n = tid; n < N; n += bd) {
        const int id = s_id[n];
        const int p = atomicAdd(&s_pos[id], 1);
        s_sorted[s_start[id] + p] = n;
    }
    __syncthreads();
    for (int g = tid; g < NP; g += bd) {
        const int c = s_cnt[g], st = s_start[g], qs = s_qstart[g];
        const int nq = (c + RB - 1) / RB;
        for (int k = 0; k < nq; ++k) {
            int* rec = ws + 16 + (size_t)(qs + k) * RECS;
            for (int r = 0; r < RB; ++r) {
                const int idx = k * RB + r;
                rec[r] = (idx < c) ? s_sorted[st + idx] : -1;
            }
            rec[RB] = g;
        }
    }
}

// ------------------------------------------------------------------ quad GEMV
// One block per (quad, h-slab). Streams W[id][h0:h0+128, :] once with float4
// loads (unroll 8 -> 8 loads in flight/thread) and applies it to the quad's
// 4 rows (16 FMA / 16B load). Partials combined via atomicAdd into zeroed out.
__global__ __launch_bounds__(128)
void quad_gemv(const int* __restrict__ ws,
               const float* __restrict__ inp,
               const float* __restrict__ params,
               const float* __restrict__ bias,
               const int* __restrict__ msg_to_p,
               const int* __restrict__ order_p,
               float* __restrict__ out, int N) {
    // bijective XCD-chunked swizzle (NB % 8 == 0): the 4 h-slabs of a quad and
    // neighboring quads (same group -> same W) share an XCD for L2 reuse.
    constexpr int q = NB / 8;
    const int b = blockIdx.x;
    const int Lg = (b & 7) * q + (b >> 3);
    const int quad = Lg >> 2;
    const int ht   = Lg & 3;

    if (quad >= ws[0]) return;
    const int* rec = ws + 16 + (size_t)quad * RECS;
    const int id = rec[RB];

    const int msg_to = *msg_to_p;
    const int order  = *order_p;
    const int tid = threadIdx.x;
    const int h0 = ht * HH;

    __shared__ float fp_s[HH][RB];   // [h][r] — one b128 broadcast per h
    // stage: HH == blockDim -> one h per thread per row
#pragma unroll
    for (int r = 0; r < RB; ++r) {
        const int row = rec[r];
        float p = 0.0f;
        if (row >= 0) {
            p = 1.0f;
            for (int i = 0; i < order; ++i)
                if (i != msg_to)
                    p *= inp[((size_t)i * N + row) * H_ + h0 + tid];
        }
        fp_s[tid][r] = p;
    }
    __syncthreads();

    const float* wp = params + (size_t)id * H_ * O_ + (size_t)h0 * O_ + 4 * tid;

    float4 a0 = make_float4(0,0,0,0), a1 = a0, a2 = a0, a3 = a0;

#define FMA1(acc, s) acc.x += (s) * w.x; acc.y += (s) * w.y; \
                     acc.z += (s) * w.z; acc.w += (s) * w.w;
#pragma unroll 8
    for (int h = 0; h < HH; ++h) {
        const float4 w = *(const float4*)wp;  wp += O_;
        const float4 f = *(const float4*)&fp_s[h][0];
        FMA1(a0, f.x) FMA1(a1, f.y) FMA1(a2, f.z) FMA1(a3, f.w)
    }
#undef FMA1

    float4 bv = make_float4(0,0,0,0);
    if (ht == 0) bv = *(const float4*)(bias + (size_t)id * O_ + 4 * tid);

#define EMIT(r, acc)                                                   \
    { const int row = rec[r];                                          \
      if (row >= 0) {                                                  \
          float* op = out + (size_t)row * O_ + 4 * tid;                \
          atomicAdd(op + 0, acc.x + bv.x);                             \
          atomicAdd(op + 1, acc.y + bv.y);                             \
          atomicAdd(op + 2, acc.z + bv.z);                             \
          atomicAdd(op + 3, acc.w + bv.w);                             \
      } }
    EMIT(0, a0) EMIT(1, a1) EMIT(2, a2) EMIT(3, a3)
#undef EMIT
}

// ---------------------------------------------------------------------- launch
extern "C" void kernel_launch(void* const* d_in, const int* in_sizes, int n_in,
                              void* d_out, int out_size, void* d_ws, size_t ws_size,
                              hipStream_t stream) {
    const int*   x      = (const int*)d_in[0];
    const int*   fact   = (const int*)d_in[1];
    const float* inp    = (const float*)d_in[2];
    const float* params = (const float*)d_in[3];
    const float* bias   = (const float*)d_in[4];
    const int*   msg_to = (const int*)d_in[5];
    const int*   order  = (const int*)d_in[6];
    float*       out    = (float*)d_out;

    const int N = in_sizes[1] / 2;   // 1024
    int* ws = (int*)d_ws;

    hipMemsetAsync(d_out, 0, (size_t)N * O_ * sizeof(float), stream);

    hipLaunchKernelGGL(build_quads, dim3(1), dim3(256), 0, stream,
                       x, fact, ws, N);

    hipLaunchKernelGGL(quad_gemv, dim3(NB), dim3(128), 0, stream,
                       ws, inp, params, bias, msg_to, order, out, N);
}

// Round 6
// 60.246 us; speedup vs baseline: 1.3763x; 1.2585x over previous
//
#include <hip/hip_runtime.h>

#define NATOMS 13
#define NP (NATOMS * NATOMS)   // 169

constexpr int N_ = 1024;   // rows
constexpr int H_ = 512;    // inner dim
constexpr int O_ = 512;    // output dim
constexpr int RB = 4;      // rows per W stream (quad)
constexpr int OSPLIT = 4;
constexpr int OC = O_ / OSPLIT;        // 128 cols per panel
constexpr int MAXQUAD = 384;           // >= sum ceil(c_g/4) worst case
constexpr int NB = MAXQUAD * OSPLIT;   // 1536 blocks (div by 8)
constexpr int RECS = 8;    // ints per quad record: rows[4], id, pad

// ws ints: [0] nquads; records at ws+16: [quad*RECS + {0..3}] rows, [+4] id
// ----------------------------------------------------------------- build quads
__global__ void build_quads(const int* __restrict__ x,
                            const int* __restrict__ fact,
                            int* __restrict__ ws, int N) {
    __shared__ int s_id[N_];
    __shared__ int s_cnt[NP];
    __shared__ int s_start[NP];
    __shared__ int s_qstart[NP];
    __shared__ int s_pos[NP];
    __shared__ int s_sorted[N_];
    const int tid = threadIdx.x, bd = blockDim.x;

    for (int i = tid; i < NP; i += bd) { s_cnt[i] = 0; s_pos[i] = 0; }
    __syncthreads();
    for (int n = tid; n < N; n += bd) {
        const int f0 = fact[2 * n];
        const int id = x[f0 * 3 + 1] * NATOMS + x[f0 * 3 + 2];
        s_id[n] = id;
        atomicAdd(&s_cnt[id], 1);
    }
    __syncthreads();
    if (tid == 0) {
        int run = 0, qrun = 0;
        for (int g = 0; g < NP; ++g) {
            s_start[g] = run;   run  += s_cnt[g];
            s_qstart[g] = qrun; qrun += (s_cnt[g] + RB - 1) / RB;
        }
        ws[0] = qrun;  // nquads
    }
    __syncthreads();
    for (int n = tid; n < N; n += bd) {
        const int id = s_id[n];
        const int p = atomicAdd(&s_pos[id], 1);
        s_sorted[s_start[id] + p] = n;
    }
    __syncthreads();
    for (int g = tid; g < NP; g += bd) {
        const int c = s_cnt[g], st = s_start[g], qs = s_qstart[g];
        const int nq = (c + RB - 1) / RB;
        for (int k = 0; k < nq; ++k) {
            int* rec = ws + 16 + (size_t)(qs + k) * RECS;
            for (int r = 0; r < RB; ++r) {
                const int idx = k * RB + r;
                rec[r] = (idx < c) ? s_sorted[st + idx] : -1;
            }
            rec[RB] = g;
        }
    }
}

// ------------------------------------------------------------------ quad GEMV
// One block per (quad, o-panel). Streams W[id][0:512, o0:o0+128] once with
// float4 loads (4 h-rows/iter via thread sub-groups, unroll 8 -> 8 loads in
// flight/thread), 16 FMA / 16B load. End: one LDS reduce across sub-groups,
// bias add, ONE direct float4 store per output element. No atomics, no memset.
__global__ __launch_bounds__(128)
void quad_gemv(const int* __restrict__ ws,
               const float* __restrict__ inp,
               const float* __restrict__ params,
               const float* __restrict__ bias,
               const int* __restrict__ msg_to_p,
               const int* __restrict__ order_p,
               float* __restrict__ out, int N) {
    // bijective XCD-chunked swizzle (NB % 8 == 0): the 4 o-panels of a quad
    // and neighboring quads (same group -> same W) share an XCD for L2 reuse.
    constexpr int q = NB / 8;
    const int b = blockIdx.x;
    const int Lg = (b & 7) * q + (b >> 3);
    const int quad = Lg >> 2;
    const int op   = Lg & 3;

    if (quad >= ws[0]) return;
    const int* rec = ws + 16 + (size_t)quad * RECS;
    const int id = rec[RB];

    const int msg_to = *msg_to_p;
    const int order  = *order_p;
    const int tid = threadIdx.x;
    const int sub = tid >> 5;        // 0..3: h-row within each 4-row step
    const int l   = tid & 31;        // col quad within panel
    const int o0  = op * OC;

    __shared__ float  fp_s[H_][RB];      // 8 KB, [h][r]
    __shared__ float4 red[4][4][32];     // 8 KB, [sub][r][l]

    // stage fact_prod for all H (coalesced 512B per (r,k,factor))
#pragma unroll
    for (int r = 0; r < RB; ++r) {
        const int row = rec[r];
        if (row >= 0) {
#pragma unroll
            for (int k = 0; k < H_ / 128; ++k) {
                const int h = k * 128 + tid;
                float p = 1.0f;
                for (int i = 0; i < order; ++i)
                    if (i != msg_to)
                        p *= inp[((size_t)i * N + row) * H_ + h];
                fp_s[h][r] = p;
            }
        } else {
#pragma unroll
            for (int k = 0; k < H_ / 128; ++k) fp_s[k * 128 + tid][r] = 0.0f;
        }
    }
    __syncthreads();

    const float* wp = params + (size_t)id * H_ * O_
                    + (size_t)sub * O_ + o0 + 4 * l;

    float4 a0 = make_float4(0,0,0,0), a1 = a0, a2 = a0, a3 = a0;

#define FMA1(acc, s) acc.x += (s) * w.x; acc.y += (s) * w.y; \
                     acc.z += (s) * w.z; acc.w += (s) * w.w;
#pragma unroll 8
    for (int hb = 0; hb < H_; hb += 4) {
        const float4 w = *(const float4*)wp;  wp += 4 * O_;
        const float4 f = *(const float4*)&fp_s[hb + sub][0];
        FMA1(a0, f.x) FMA1(a1, f.y) FMA1(a2, f.z) FMA1(a3, f.w)
    }
#undef FMA1

    // cross-subgroup reduce (once per block)
    red[sub][0][l] = a0;
    red[sub][1][l] = a1;
    red[sub][2][l] = a2;
    red[sub][3][l] = a3;
    __syncthreads();

    const int row = rec[sub];
    if (row >= 0) {
        const float4 p0 = red[0][sub][l];
        const float4 p1 = red[1][sub][l];
        const float4 p2 = red[2][sub][l];
        const float4 p3 = red[3][sub][l];
        const float4 bv = *(const float4*)(bias + (size_t)id * O_ + o0 + 4 * l);
        float4 s;
        s.x = p0.x + p1.x + p2.x + p3.x + bv.x;
        s.y = p0.y + p1.y + p2.y + p3.y + bv.y;
        s.z = p0.z + p1.z + p2.z + p3.z + bv.z;
        s.w = p0.w + p1.w + p2.w + p3.w + bv.w;
        *(float4*)(out + (size_t)row * O_ + o0 + 4 * l) = s;
    }
}

// ---------------------------------------------------------------------- launch
extern "C" void kernel_launch(void* const* d_in, const int* in_sizes, int n_in,
                              void* d_out, int out_size, void* d_ws, size_t ws_size,
                              hipStream_t stream) {
    const int*   x      = (const int*)d_in[0];
    const int*   fact   = (const int*)d_in[1];
    const float* inp    = (const float*)d_in[2];
    const float* params = (const float*)d_in[3];
    const float* bias   = (const float*)d_in[4];
    const int*   msg_to = (const int*)d_in[5];
    const int*   order  = (const int*)d_in[6];
    float*       out    = (float*)d_out;

    const int N = in_sizes[1] / 2;   // 1024
    int* ws = (int*)d_ws;

    hipLaunchKernelGGL(build_quads, dim3(1), dim3(256), 0, stream,
                       x, fact, ws, N);

    hipLaunchKernelGGL(quad_gemv, dim3(NB), dim3(128), 0, stream,
                       ws, inp, params, bias, msg_to, order, out, N);
}

// Round 7
// 59.691 us; speedup vs baseline: 1.3890x; 1.0093x over previous
//
#include <hip/hip_runtime.h>

#define NATOMS 13
#define NP (NATOMS * NATOMS)   // 169

constexpr int N_ = 1024;   // rows
constexpr int H_ = 512;    // inner dim
constexpr int O_ = 512;    // output dim
constexpr int RB = 4;      // rows per W stream (quad)
constexpr int OSPLIT = 4;
constexpr int OC = O_ / OSPLIT;        // 128 cols per panel
constexpr int MAXQUAD = 384;           // >= sum ceil(c_g/4) worst case
constexpr int NB = MAXQUAD * OSPLIT;   // 1536 blocks (div by 8)
constexpr int RECS = 8;    // ints per quad record: rows[4], id, pad

// ws ints: [0] nquads; records at ws+16: [quad*RECS + {0..3}] rows, [+4] id
// ----------------------------------------------------------------- build quads
__global__ void build_quads(const int* __restrict__ x,
                            const int* __restrict__ fact,
                            int* __restrict__ ws, int N) {
    __shared__ int s_id[N_];
    __shared__ int s_cnt[NP];
    __shared__ int s_start[NP];
    __shared__ int s_qstart[NP];
    __shared__ int s_pos[NP];
    __shared__ int s_sorted[N_];
    const int tid = threadIdx.x, bd = blockDim.x;

    for (int i = tid; i < NP; i += bd) { s_cnt[i] = 0; s_pos[i] = 0; }
    __syncthreads();
    for (int n = tid; n < N; n += bd) {
        const int f0 = fact[2 * n];
        const int id = x[f0 * 3 + 1] * NATOMS + x[f0 * 3 + 2];
        s_id[n] = id;
        atomicAdd(&s_cnt[id], 1);
    }
    __syncthreads();
    if (tid == 0) {
        int run = 0, qrun = 0;
        for (int g = 0; g < NP; ++g) {
            s_start[g] = run;   run  += s_cnt[g];
            s_qstart[g] = qrun; qrun += (s_cnt[g] + RB - 1) / RB;
        }
        ws[0] = qrun;  // nquads
    }
    __syncthreads();
    for (int n = tid; n < N; n += bd) {
        const int id = s_id[n];
        const int p = atomicAdd(&s_pos[id], 1);
        s_sorted[s_start[id] + p] = n;
    }
    __syncthreads();
    for (int g = tid; g < NP; g += bd) {
        const int c = s_cnt[g], st = s_start[g], qs = s_qstart[g];
        const int nq = (c + RB - 1) / RB;
        for (int k = 0; k < nq; ++k) {
            int* rec = ws + 16 + (size_t)(qs + k) * RECS;
            for (int r = 0; r < RB; ++r) {
                const int idx = k * RB + r;
                rec[r] = (idx < c) ? s_sorted[st + idx] : -1;
            }
            rec[RB] = g;
        }
    }
}

// ------------------------------------------------------------------ quad GEMV
// One block per (quad, o-panel). Streams W[id][0:512, o0:o0+128] with an
// EXPLICIT 8-deep ping-pong register pipeline (wA/wB, all indices static):
// 8 float4 loads are in flight while the previous 8 are consumed.
// End: one LDS reduce across sub-groups, bias, ONE float4 store. No atomics.
__global__ __launch_bounds__(128)
void quad_gemv(const int* __restrict__ ws,
               const float* __restrict__ inp,
               const float* __restrict__ params,
               const float* __restrict__ bias,
               const int* __restrict__ msg_to_p,
               const int* __restrict__ order_p,
               float* __restrict__ out, int N) {
    // bijective XCD-chunked swizzle (NB % 8 == 0)
    constexpr int q = NB / 8;
    const int b = blockIdx.x;
    const int Lg = (b & 7) * q + (b >> 3);
    const int quad = Lg >> 2;
    const int op   = Lg & 3;

    if (quad >= ws[0]) return;
    const int* rec = ws + 16 + (size_t)quad * RECS;
    const int id = rec[RB];

    const int msg_to = *msg_to_p;
    const int order  = *order_p;
    const int tid = threadIdx.x;
    const int sub = tid >> 5;        // 0..3: h-row within each 4-row step
    const int l   = tid & 31;        // col quad within panel
    const int o0  = op * OC;

    __shared__ float  fp_s[H_][RB];      // 8 KB, [h][r]
    __shared__ float4 red[4][4][32];     // 8 KB, [sub][r][l]

    // stage fact_prod for all H (coalesced 512B per (r,k,factor))
#pragma unroll
    for (int r = 0; r < RB; ++r) {
        const int row = rec[r];
        if (row >= 0) {
#pragma unroll
            for (int k = 0; k < H_ / 128; ++k) {
                const int h = k * 128 + tid;
                float p = 1.0f;
                for (int i = 0; i < order; ++i)
                    if (i != msg_to)
                        p *= inp[((size_t)i * N + row) * H_ + h];
                fp_s[h][r] = p;
            }
        } else {
#pragma unroll
            for (int k = 0; k < H_ / 128; ++k) fp_s[k * 128 + tid][r] = 0.0f;
        }
    }
    __syncthreads();

    const float* __restrict__ wbase =
        params + (size_t)id * H_ * O_ + (size_t)sub * O_ + o0 + 4 * l;

    float4 a0 = make_float4(0,0,0,0), a1 = a0, a2 = a0, a3 = a0;

#define LOADW(W, hb)                                                  \
    W[0] = *(const float4*)(wbase + (size_t)((hb) +  0) * O_);        \
    W[1] = *(const float4*)(wbase + (size_t)((hb) +  4) * O_);        \
    W[2] = *(const float4*)(wbase + (size_t)((hb) +  8) * O_);        \
    W[3] = *(const float4*)(wbase + (size_t)((hb) + 12) * O_);        \
    W[4] = *(const float4*)(wbase + (size_t)((hb) + 16) * O_);        \
    W[5] = *(const float4*)(wbase + (size_t)((hb) + 20) * O_);        \
    W[6] = *(const float4*)(wbase + (size_t)((hb) + 24) * O_);        \
    W[7] = *(const float4*)(wbase + (size_t)((hb) + 28) * O_);

#define CONS1(wv, h)                                                  \
    { const float4 f = *(const float4*)&fp_s[(h) + sub][0];           \
      a0.x += f.x * wv.x; a0.y += f.x * wv.y;                         \
      a0.z += f.x * wv.z; a0.w += f.x * wv.w;                         \
      a1.x += f.y * wv.x; a1.y += f.y * wv.y;                         \
      a1.z += f.y * wv.z; a1.w += f.y * wv.w;                         \
      a2.x += f.z * wv.x; a2.y += f.z * wv.y;                         \
      a2.z += f.z * wv.z; a2.w += f.z * wv.w;                         \
      a3.x += f.w * wv.x; a3.y += f.w * wv.y;                         \
      a3.z += f.w * wv.z; a3.w += f.w * wv.w; }

#define CONSUME(W, hb)                                                \
    CONS1(W[0], (hb) +  0) CONS1(W[1], (hb) +  4)                     \
    CONS1(W[2], (hb) +  8) CONS1(W[3], (hb) + 12)                     \
    CONS1(W[4], (hb) + 16) CONS1(W[5], (hb) + 20)                     \
    CONS1(W[6], (hb) + 24) CONS1(W[7], (hb) + 28)

    float4 wA[8], wB[8];
    LOADW(wA, 0)
#pragma unroll
    for (int hb = 0; hb < H_; hb += 64) {
        LOADW(wB, hb + 32)         // next 8 in flight while consuming wA
        CONSUME(wA, hb)
        if (hb + 64 < H_) { LOADW(wA, hb + 64) }   // static: resolved at compile time
        CONSUME(wB, hb + 32)
    }
#undef LOADW
#undef CONS1
#undef CONSUME

    // cross-subgroup reduce (once per block)
    red[sub][0][l] = a0;
    red[sub][1][l] = a1;
    red[sub][2][l] = a2;
    red[sub][3][l] = a3;
    __syncthreads();

    const int row = rec[sub];
    if (row >= 0) {
        const float4 p0 = red[0][sub][l];
        const float4 p1 = red[1][sub][l];
        const float4 p2 = red[2][sub][l];
        const float4 p3 = red[3][sub][l];
        const float4 bv = *(const float4*)(bias + (size_t)id * O_ + o0 + 4 * l);
        float4 s;
        s.x = p0.x + p1.x + p2.x + p3.x + bv.x;
        s.y = p0.y + p1.y + p2.y + p3.y + bv.y;
        s.z = p0.z + p1.z + p2.z + p3.z + bv.z;
        s.w = p0.w + p1.w + p2.w + p3.w + bv.w;
        *(float4*)(out + (size_t)row * O_ + o0 + 4 * l) = s;
    }
}

// ---------------------------------------------------------------------- launch
extern "C" void kernel_launch(void* const* d_in, const int* in_sizes, int n_in,
                              void* d_out, int out_size, void* d_ws, size_t ws_size,
                              hipStream_t stream) {
    const int*   x      = (const int*)d_in[0];
    const int*   fact   = (const int*)d_in[1];
    const float* inp    = (const float*)d_in[2];
    const float* params = (const float*)d_in[3];
    const float* bias   = (const float*)d_in[4];
    const int*   msg_to = (const int*)d_in[5];
    const int*   order  = (const int*)d_in[6];
    float*       out    = (float*)d_out;

    const int N = in_sizes[1] / 2;   // 1024
    int* ws = (int*)d_ws;

    hipLaunchKernelGGL(build_quads, dim3(1), dim3(256), 0, stream,
                       x, fact, ws, N);

    hipLaunchKernelGGL(quad_gemv, dim3(NB), dim3(128), 0, stream,
                       ws, inp, params, bias, msg_to, order, out, N);
}